// Round 5
// baseline (620.050 us; speedup 1.0000x reference)
//
#include <hip/hip_runtime.h>
#include <hip/hip_bf16.h>
#include <math.h>

#define N_NODES 50000
#define N_EDGES 800000
#define F_IN 512
#define HID 128
#define NCLS 40
#define NBLK 196   // ceil(N_NODES/256)

typedef unsigned short u16;
typedef __attribute__((ext_vector_type(8))) short short8;
typedef __attribute__((ext_vector_type(8))) unsigned short u16x8;
typedef __attribute__((ext_vector_type(4))) float f32x4;

__device__ inline u16 f2bf(float f) {
    unsigned int u = __float_as_uint(f);
    unsigned int r = (u + 0x7FFFu + ((u >> 16) & 1u)) >> 16;
    return (u16)r;
}
__device__ inline float bf2f(u16 b) {
    return __uint_as_float(((unsigned int)b) << 16);
}

// ---------------- CSR build ----------------

__global__ void k_zero_deg(int* __restrict__ deg) {
    int i = blockIdx.x * 256 + threadIdx.x;
    if (i < N_NODES) deg[i] = 0;
}

__global__ void k_count(const int* __restrict__ row, int* __restrict__ deg) {
    int e = blockIdx.x * 256 + threadIdx.x;
    if (e < N_EDGES) atomicAdd(&deg[row[e]], 1);
}

__global__ void k_dinv(const int* __restrict__ deg, float* __restrict__ dinv) {
    int i = blockIdx.x * 256 + threadIdx.x;
    if (i < N_NODES) dinv[i] = rsqrtf((float)(deg[i] + 1));  // +1 self-loop
}

__device__ inline int wave_incl_scan(int v, int lane) {
    #pragma unroll
    for (int off = 1; off < 64; off <<= 1) {
        int g = __shfl_up(v, off);
        if (lane >= off) v += g;
    }
    return v;
}

__global__ void k_scan_partial(const int* __restrict__ deg, int* __restrict__ blocksum) {
    int t = threadIdx.x;
    int i = blockIdx.x * 256 + t;
    int v = (i < N_NODES) ? deg[i] : 0;
    #pragma unroll
    for (int off = 32; off; off >>= 1) v += __shfl_xor(v, off);
    __shared__ int ws[4];
    if ((t & 63) == 0) ws[t >> 6] = v;
    __syncthreads();
    if (t == 0) blocksum[blockIdx.x] = ws[0] + ws[1] + ws[2] + ws[3];
}

__global__ void k_scan_block(const int* __restrict__ blocksum, int* __restrict__ blockoff) {
    int t = threadIdx.x, lane = t & 63, w = t >> 6;
    int v = (t < NBLK) ? blocksum[t] : 0;
    int incl = wave_incl_scan(v, lane);
    __shared__ int wsum[4];
    if (lane == 63) wsum[w] = incl;
    __syncthreads();
    int woff = 0;
    for (int j = 0; j < w; ++j) woff += wsum[j];
    incl += woff;
    if (t < NBLK) blockoff[t] = incl - v;
    if (t == NBLK - 1) blockoff[NBLK] = incl;
}

__global__ void k_scan_final(const int* __restrict__ deg, const int* __restrict__ blockoff,
                             int* __restrict__ rowptr, int* __restrict__ cursor) {
    int t = threadIdx.x, lane = t & 63, w = t >> 6;
    int i = blockIdx.x * 256 + t;
    int d = (i < N_NODES) ? deg[i] : 0;
    int incl = wave_incl_scan(d, lane);
    __shared__ int wsum[4];
    if (lane == 63) wsum[w] = incl;
    __syncthreads();
    int woff = 0;
    for (int j = 0; j < w; ++j) woff += wsum[j];
    int excl = incl - d + woff + blockoff[blockIdx.x];
    if (i < N_NODES) { rowptr[i] = excl; cursor[i] = excl; }
    if (i == 0) rowptr[N_NODES] = blockoff[NBLK];
}

__global__ void k_scatter(const int* __restrict__ row, const int* __restrict__ col,
                          const float* __restrict__ dinv, int* __restrict__ cursor,
                          int* __restrict__ csr_col, float* __restrict__ csr_nrm) {
    int e = blockIdx.x * 256 + threadIdx.x;
    if (e >= N_EDGES) return;
    int r = row[e], c = col[e];
    int pos = atomicAdd(&cursor[r], 1);
    csr_col[pos] = c;
    csr_nrm[pos] = dinv[r] * dinv[c];
}

// ---------------- degree-bucket counting sort -> node_order ----------------

__global__ void k_hist_zero(int* __restrict__ hist) {
    if (threadIdx.x < 64) hist[threadIdx.x] = 0;
}

__global__ void k_hist(const int* __restrict__ deg, int* __restrict__ hist) {
    int i = blockIdx.x * 256 + threadIdx.x;
    if (i < N_NODES) atomicAdd(&hist[min(deg[i], 63)], 1);
}

__global__ void k_hist_scan(const int* __restrict__ hist, int* __restrict__ bcur) {
    int t = threadIdx.x;  // 64 threads
    int v = hist[t];
    int incl = wave_incl_scan(v, t);
    bcur[t] = incl - v;
}

__global__ void k_order(const int* __restrict__ deg, int* __restrict__ bcur,
                        int* __restrict__ node_order) {
    int i = blockIdx.x * 256 + threadIdx.x;
    if (i < N_NODES) {
        int p = atomicAdd(&bcur[min(deg[i], 63)], 1);
        node_order[p] = i;
    }
}

// ---------------- weight transpose + bf16 hi/lo split ----------------

__global__ void k_wsplit(const float* __restrict__ W, u16* __restrict__ Whi,
                         u16* __restrict__ Wlo, int Kdim) {
    int idx = blockIdx.x * 256 + threadIdx.x;
    if (idx >= Kdim * 128) return;
    int k = idx >> 7, n = idx & 127;
    float f = W[idx];
    u16 hb = f2bf(f);
    u16 lb = f2bf(f - bf2f(hb));
    int p = ((k >> 3) & 3) ^ (n & 3);
    int kp = (k & ~31) | (p << 3) | (k & 7);
    Whi[(size_t)n * Kdim + kp] = hb;
    Wlo[(size_t)n * Kdim + kp] = lb;
}

// ---------------- MFMA GEMM: [M x K] f32 @ [K x 128] -> [M x 128] bf16 ----

template<int K, bool RELU>
__global__ void k_gemm_mfma(const float* __restrict__ A, const u16* __restrict__ Whi,
                            const u16* __restrict__ Wlo, u16* __restrict__ C, int M) {
    __shared__ u16 sAhi[64 * 32];
    __shared__ u16 sAlo[64 * 32];
    __shared__ u16 sBhi[128 * 32];
    __shared__ u16 sBlo[128 * 32];

    const int t = threadIdx.x;
    const int w = t >> 6;
    const int l = t & 63;
    const int ln = l & 15;
    const int h = l >> 4;
    const int row0 = blockIdx.x * 64;

    const int ar = t >> 2;
    const int aslot = t & 3;
    const int arow = row0 + ar;
    const bool aval = arow < M;
    const int aswz = (aslot ^ (ar & 3));
    const int bn = t >> 2;
    const int bs = t & 3;

    f32x4 acc[4][2];
    #pragma unroll
    for (int i = 0; i < 4; ++i)
        #pragma unroll
        for (int j = 0; j < 2; ++j)
            acc[i][j] = (f32x4){0.f, 0.f, 0.f, 0.f};

    for (int k0 = 0; k0 < K; k0 += 32) {
        float va[8];
        if (aval) {
            float4 v0 = *reinterpret_cast<const float4*>(A + (size_t)arow * K + k0 + aslot * 8);
            float4 v1 = *reinterpret_cast<const float4*>(A + (size_t)arow * K + k0 + aslot * 8 + 4);
            va[0] = v0.x; va[1] = v0.y; va[2] = v0.z; va[3] = v0.w;
            va[4] = v1.x; va[5] = v1.y; va[6] = v1.z; va[7] = v1.w;
        } else {
            #pragma unroll
            for (int q = 0; q < 8; ++q) va[q] = 0.f;
        }
        u16x8 hv, lv;
        #pragma unroll
        for (int q = 0; q < 8; ++q) {
            float f = va[q];
            if (RELU) f = fmaxf(f, 0.f);
            u16 hb = f2bf(f);
            hv[q] = hb;
            lv[q] = f2bf(f - bf2f(hb));
        }
        *reinterpret_cast<u16x8*>(sAhi + ar * 32 + aswz * 8) = hv;
        *reinterpret_cast<u16x8*>(sAlo + ar * 32 + aswz * 8) = lv;

        {
            const u16* gh0 = Whi + (size_t)bn * K + k0 + bs * 8;
            const u16* gh1 = Whi + (size_t)(bn + 64) * K + k0 + bs * 8;
            const u16* gl0 = Wlo + (size_t)bn * K + k0 + bs * 8;
            const u16* gl1 = Wlo + (size_t)(bn + 64) * K + k0 + bs * 8;
            *reinterpret_cast<uint4*>(sBhi + bn * 32 + bs * 8)        = *reinterpret_cast<const uint4*>(gh0);
            *reinterpret_cast<uint4*>(sBhi + (bn + 64) * 32 + bs * 8) = *reinterpret_cast<const uint4*>(gh1);
            *reinterpret_cast<uint4*>(sBlo + bn * 32 + bs * 8)        = *reinterpret_cast<const uint4*>(gl0);
            *reinterpret_cast<uint4*>(sBlo + (bn + 64) * 32 + bs * 8) = *reinterpret_cast<const uint4*>(gl1);
        }
        __syncthreads();

        short8 ah[4], al[4], bh[2], bl[2];
        #pragma unroll
        for (int i = 0; i < 4; ++i) {
            int r = i * 16 + ln;
            int idx = r * 32 + ((h ^ (r & 3)) << 3);
            ah[i] = *reinterpret_cast<const short8*>(sAhi + idx);
            al[i] = *reinterpret_cast<const short8*>(sAlo + idx);
        }
        #pragma unroll
        for (int j = 0; j < 2; ++j) {
            int n = w * 32 + j * 16 + ln;
            int idx = n * 32 + ((h ^ (n & 3)) << 3);
            bh[j] = *reinterpret_cast<const short8*>(sBhi + idx);
            bl[j] = *reinterpret_cast<const short8*>(sBlo + idx);
        }

        #pragma unroll
        for (int i = 0; i < 4; ++i)
            #pragma unroll
            for (int j = 0; j < 2; ++j) {
                acc[i][j] = __builtin_amdgcn_mfma_f32_16x16x32_bf16(ah[i], bh[j], acc[i][j], 0, 0, 0);
                acc[i][j] = __builtin_amdgcn_mfma_f32_16x16x32_bf16(ah[i], bl[j], acc[i][j], 0, 0, 0);
                acc[i][j] = __builtin_amdgcn_mfma_f32_16x16x32_bf16(al[i], bh[j], acc[i][j], 0, 0, 0);
            }
        __syncthreads();
    }

    // epilogue: bf16 output
    #pragma unroll
    for (int i = 0; i < 4; ++i) {
        #pragma unroll
        for (int v = 0; v < 4; ++v) {
            int gr = row0 + i * 16 + h * 4 + v;
            if (gr < M) {
                #pragma unroll
                for (int j = 0; j < 2; ++j) {
                    int col = w * 32 + j * 16 + ln;
                    C[(size_t)gr * 128 + col] = f2bf(acc[i][j][v]);
                }
            }
        }
    }
}

// ---------------- GEMM: [M x 128] @ [128 x 40] -> [M x 40] ----------------

template<bool RELU>
__global__ void k_gemm40(const float* __restrict__ A, const float* __restrict__ W,
                         float* __restrict__ C, int M) {
    __shared__ float As[64][132];
    __shared__ float Ws[128][40];
    int t = threadIdx.x;
    int row0 = blockIdx.x * 64;
    #pragma unroll
    for (int i = 0; i < 8; ++i) {
        int fidx = t + i * 256;
        int r = fidx >> 5, c = (fidx & 31) << 2;
        int gr = row0 + r;
        float4 v = make_float4(0.f, 0.f, 0.f, 0.f);
        if (gr < M) v = *reinterpret_cast<const float4*>(A + (size_t)gr * 128 + c);
        if (RELU) {
            v.x = fmaxf(v.x, 0.f); v.y = fmaxf(v.y, 0.f);
            v.z = fmaxf(v.z, 0.f); v.w = fmaxf(v.w, 0.f);
        }
        *reinterpret_cast<float4*>(&As[r][c]) = v;
    }
    #pragma unroll
    for (int i = 0; i < 5; ++i) {
        int fidx = t + i * 256;
        int r = fidx / 10, c = (fidx % 10) << 2;
        float4 v = *reinterpret_cast<const float4*>(W + r * 40 + c);
        *reinterpret_cast<float4*>(&Ws[r][c]) = v;
    }
    __syncthreads();
    int r = t >> 2;
    int cg = t & 3;
    float acc[10];
    #pragma unroll
    for (int j = 0; j < 10; ++j) acc[j] = 0.0f;
    for (int k = 0; k < 128; ++k) {
        float a = As[r][k];
        #pragma unroll
        for (int j = 0; j < 10; ++j)
            acc[j] = fmaf(a, Ws[k][cg * 10 + j], acc[j]);
    }
    int gr = row0 + r;
    if (gr < M) {
        #pragma unroll
        for (int j = 0; j < 10; ++j)
            C[(size_t)gr * 40 + cg * 10 + j] = acc[j];
    }
}

// ---------------- CSR aggregation, bf16 h (NF=128) ----------------
// out[i][:] = bf2f(h[i][:])*dinv[i]^2 + bias + sum_e bf2f(h[col])*nrm
// 32 lanes per node, 4 features (8B) each; node order degree-sorted.

__global__ void k_agg_csr_bf(const u16* __restrict__ h, const float* __restrict__ dinv,
                             const float* __restrict__ bias,
                             const int* __restrict__ rowptr, const int* __restrict__ csr_col,
                             const float* __restrict__ csr_nrm,
                             const int* __restrict__ node_order, float* __restrict__ out) {
    int gid = blockIdx.x * 256 + threadIdx.x;
    if (gid >= N_NODES * 32) return;
    int i = node_order[gid >> 5];
    int q = (gid & 31) * 4;
    float di = dinv[i];
    float s = di * di;
    ushort4 hv = *reinterpret_cast<const ushort4*>(h + (size_t)i * 128 + q);
    float4 bv = *reinterpret_cast<const float4*>(bias + q);
    float4 acc;
    acc.x = fmaf(bf2f(hv.x), s, bv.x);
    acc.y = fmaf(bf2f(hv.y), s, bv.y);
    acc.z = fmaf(bf2f(hv.z), s, bv.z);
    acc.w = fmaf(bf2f(hv.w), s, bv.w);
    int e = rowptr[i], e1 = rowptr[i + 1];
    for (; e + 1 < e1; e += 2) {
        int c0 = csr_col[e], c1 = csr_col[e + 1];
        float n0 = csr_nrm[e], n1 = csr_nrm[e + 1];
        ushort4 v0 = *reinterpret_cast<const ushort4*>(h + (size_t)c0 * 128 + q);
        ushort4 v1 = *reinterpret_cast<const ushort4*>(h + (size_t)c1 * 128 + q);
        acc.x = fmaf(bf2f(v0.x), n0, acc.x);
        acc.y = fmaf(bf2f(v0.y), n0, acc.y);
        acc.z = fmaf(bf2f(v0.z), n0, acc.z);
        acc.w = fmaf(bf2f(v0.w), n0, acc.w);
        acc.x = fmaf(bf2f(v1.x), n1, acc.x);
        acc.y = fmaf(bf2f(v1.y), n1, acc.y);
        acc.z = fmaf(bf2f(v1.z), n1, acc.z);
        acc.w = fmaf(bf2f(v1.w), n1, acc.w);
    }
    if (e < e1) {
        int c0 = csr_col[e];
        float n0 = csr_nrm[e];
        ushort4 v0 = *reinterpret_cast<const ushort4*>(h + (size_t)c0 * 128 + q);
        acc.x = fmaf(bf2f(v0.x), n0, acc.x);
        acc.y = fmaf(bf2f(v0.y), n0, acc.y);
        acc.z = fmaf(bf2f(v0.z), n0, acc.z);
        acc.w = fmaf(bf2f(v0.w), n0, acc.w);
    }
    *reinterpret_cast<float4*>(out + (size_t)i * 128 + q) = acc;
}

// ---------------- CSR aggregation, f32 h (NF=40, layer 3) ----------------

__global__ void k_agg_csr40(const float* __restrict__ h, const float* __restrict__ dinv,
                            const float* __restrict__ bias,
                            const int* __restrict__ rowptr, const int* __restrict__ csr_col,
                            const float* __restrict__ csr_nrm,
                            const int* __restrict__ node_order, float* __restrict__ out) {
    const int TPN = 10;
    int gid = blockIdx.x * 256 + threadIdx.x;
    if (gid >= N_NODES * TPN) return;
    int i = node_order[gid / TPN];
    int q = (gid % TPN) * 4;
    float di = dinv[i];
    float s = di * di;
    float4 hv = *reinterpret_cast<const float4*>(h + (size_t)i * 40 + q);
    float4 bv = *reinterpret_cast<const float4*>(bias + q);
    float4 acc;
    acc.x = fmaf(hv.x, s, bv.x);
    acc.y = fmaf(hv.y, s, bv.y);
    acc.z = fmaf(hv.z, s, bv.z);
    acc.w = fmaf(hv.w, s, bv.w);
    int e1 = rowptr[i + 1];
    for (int e = rowptr[i]; e < e1; ++e) {
        int c = csr_col[e];
        float nv = csr_nrm[e];
        float4 v = *reinterpret_cast<const float4*>(h + (size_t)c * 40 + q);
        acc.x = fmaf(v.x, nv, acc.x);
        acc.y = fmaf(v.y, nv, acc.y);
        acc.z = fmaf(v.z, nv, acc.z);
        acc.w = fmaf(v.w, nv, acc.w);
    }
    *reinterpret_cast<float4*>(out + (size_t)i * 40 + q) = acc;
}

// ---------------- log_softmax (in-place, one wave per row) ----------------

__global__ void k_logsoftmax(float* __restrict__ out) {
    int wave = threadIdx.x >> 6, lane = threadIdx.x & 63;
    int rowi = blockIdx.x * 4 + wave;
    if (rowi >= N_NODES) return;
    float v = (lane < NCLS) ? out[(size_t)rowi * NCLS + lane] : -INFINITY;
    float m = v;
    #pragma unroll
    for (int off = 32; off; off >>= 1) m = fmaxf(m, __shfl_xor(m, off));
    float ex = (lane < NCLS) ? expf(v - m) : 0.0f;
    float s = ex;
    #pragma unroll
    for (int off = 32; off; off >>= 1) s += __shfl_xor(s, off);
    float ls = logf(s);
    if (lane < NCLS) out[(size_t)rowi * NCLS + lane] = v - m - ls;
}

// ---------------- launch ----------------

extern "C" void kernel_launch(void* const* d_in, const int* in_sizes, int n_in,
                              void* d_out, int out_size, void* d_ws, size_t ws_size,
                              hipStream_t stream) {
    const float* x  = (const float*)d_in[0];
    const int* ei   = (const int*)d_in[1];
    const float* W1 = (const float*)d_in[2];
    const float* b1 = (const float*)d_in[3];
    const float* W2 = (const float*)d_in[4];
    const float* b2 = (const float*)d_in[5];
    const float* W3 = (const float*)d_in[6];
    const float* b3 = (const float*)d_in[7];
    float* out = (float*)d_out;

    const int* row = ei;             // targets
    const int* col = ei + N_EDGES;   // sources

    char* ws = (char*)d_ws;
    int*   deg      = (int*)ws;   ws += sizeof(int) * N_NODES;
    int*   rowptr   = (int*)ws;   ws += sizeof(int) * 50004;
    int*   cursor   = (int*)ws;   ws += sizeof(int) * N_NODES;
    int*   blocksum = (int*)ws;   ws += sizeof(int) * NBLK;
    int*   blockoff = (int*)ws;   ws += sizeof(int) * 204;
    int*   hist     = (int*)ws;   ws += sizeof(int) * 64;
    int*   bcur     = (int*)ws;   ws += sizeof(int) * 64;
    int*   norder   = (int*)ws;   ws += sizeof(int) * N_NODES;
    int*   csr_col  = (int*)ws;   ws += sizeof(int) * N_EDGES;
    float* csr_nrm  = (float*)ws; ws += sizeof(float) * N_EDGES;
    float* dinv     = (float*)ws; ws += sizeof(float) * N_NODES;
    u16*   wt1hi    = (u16*)ws;   ws += sizeof(u16) * F_IN * 128;
    u16*   wt1lo    = (u16*)ws;   ws += sizeof(u16) * F_IN * 128;
    u16*   wt2hi    = (u16*)ws;   ws += sizeof(u16) * HID * 128;
    u16*   wt2lo    = (u16*)ws;   ws += sizeof(u16) * HID * 128;
    u16*   hbuf     = (u16*)ws;   ws += sizeof(u16) * (size_t)N_NODES * HID;
    float* abuf     = (float*)ws; ws += sizeof(float) * (size_t)N_NODES * HID;
    float* h3       = (float*)ws; ws += sizeof(float) * (size_t)N_NODES * NCLS;

    const int NB_N = (N_NODES + 255) / 256;
    const int NB_E = (N_EDGES + 255) / 256;
    const int NB_G = (N_NODES + 63) / 64;

    // weight split/transpose (once)
    k_wsplit<<<(F_IN * 128 + 255) / 256, 256, 0, stream>>>(W1, wt1hi, wt1lo, F_IN);
    k_wsplit<<<(HID * 128 + 255) / 256, 256, 0, stream>>>(W2, wt2hi, wt2lo, HID);

    // CSR build (once, shared by all 3 layers)
    k_zero_deg<<<NB_N, 256, 0, stream>>>(deg);
    k_count<<<NB_E, 256, 0, stream>>>(row, deg);
    k_dinv<<<NB_N, 256, 0, stream>>>(deg, dinv);
    k_scan_partial<<<NBLK, 256, 0, stream>>>(deg, blocksum);
    k_scan_block<<<1, 256, 0, stream>>>(blocksum, blockoff);
    k_scan_final<<<NBLK, 256, 0, stream>>>(deg, blockoff, rowptr, cursor);
    k_scatter<<<NB_E, 256, 0, stream>>>(row, col, dinv, cursor, csr_col, csr_nrm);

    // degree-sorted node order (divergence reduction)
    k_hist_zero<<<1, 64, 0, stream>>>(hist);
    k_hist<<<NB_N, 256, 0, stream>>>(deg, hist);
    k_hist_scan<<<1, 64, 0, stream>>>(hist, bcur);
    k_order<<<NB_N, 256, 0, stream>>>(deg, bcur, norder);

    // layer 1 (MFMA split-precision GEMM -> bf16 h)
    k_gemm_mfma<F_IN, false><<<NB_G, 256, 0, stream>>>(x, wt1hi, wt1lo, hbuf, N_NODES);
    k_agg_csr_bf<<<(N_NODES * 32 + 255) / 256, 256, 0, stream>>>(
        hbuf, dinv, b1, rowptr, csr_col, csr_nrm, norder, abuf);

    // layer 2 (relu fused into GEMM A-staging)
    k_gemm_mfma<HID, true><<<NB_G, 256, 0, stream>>>(abuf, wt2hi, wt2lo, hbuf, N_NODES);
    k_agg_csr_bf<<<(N_NODES * 32 + 255) / 256, 256, 0, stream>>>(
        hbuf, dinv, b2, rowptr, csr_col, csr_nrm, norder, abuf);

    // layer 3
    k_gemm40<true><<<NB_G, 256, 0, stream>>>(abuf, W3, h3, N_NODES);
    k_agg_csr40<<<(N_NODES * 10 + 255) / 256, 256, 0, stream>>>(
        h3, dinv, b3, rowptr, csr_col, csr_nrm, norder, out);

    // log_softmax in-place
    k_logsoftmax<<<(N_NODES + 3) / 4, 256, 0, stream>>>(out);
}

// Round 6
// 302.938 us; speedup vs baseline: 2.0468x; 2.0468x over previous
//
#include <hip/hip_runtime.h>
#include <hip/hip_bf16.h>
#include <math.h>

#define N_NODES 50000
#define N_EDGES 800000
#define F_IN 512
#define HID 128
#define NCLS 40
#define NBLK 196   // ceil(N_NODES/256)

typedef unsigned short u16;
typedef __attribute__((ext_vector_type(8))) short short8;
typedef __attribute__((ext_vector_type(8))) unsigned short u16x8;
typedef __attribute__((ext_vector_type(4))) float f32x4;

__device__ inline u16 f2bf(float f) {
    unsigned int u = __float_as_uint(f);
    unsigned int r = (u + 0x7FFFu + ((u >> 16) & 1u)) >> 16;
    return (u16)r;
}
__device__ inline float bf2f(u16 b) {
    return __uint_as_float(((unsigned int)b) << 16);
}

// ---------------- CSR build ----------------

__global__ void k_zero_deg(int* __restrict__ deg) {
    int i = blockIdx.x * 256 + threadIdx.x;
    if (i < N_NODES) deg[i] = 0;
}

__global__ void k_count(const int* __restrict__ row, int* __restrict__ deg) {
    int e = blockIdx.x * 256 + threadIdx.x;
    if (e < N_EDGES) atomicAdd(&deg[row[e]], 1);
}

__global__ void k_dinv(const int* __restrict__ deg, float* __restrict__ dinv) {
    int i = blockIdx.x * 256 + threadIdx.x;
    if (i < N_NODES) dinv[i] = rsqrtf((float)(deg[i] + 1));  // +1 self-loop
}

__device__ inline int wave_incl_scan(int v, int lane) {
    #pragma unroll
    for (int off = 1; off < 64; off <<= 1) {
        int g = __shfl_up(v, off);
        if (lane >= off) v += g;
    }
    return v;
}

__global__ void k_scan_partial(const int* __restrict__ deg, int* __restrict__ blocksum) {
    int t = threadIdx.x;
    int i = blockIdx.x * 256 + t;
    int v = (i < N_NODES) ? deg[i] : 0;
    #pragma unroll
    for (int off = 32; off; off >>= 1) v += __shfl_xor(v, off);
    __shared__ int ws[4];
    if ((t & 63) == 0) ws[t >> 6] = v;
    __syncthreads();
    if (t == 0) blocksum[blockIdx.x] = ws[0] + ws[1] + ws[2] + ws[3];
}

__global__ void k_scan_block(const int* __restrict__ blocksum, int* __restrict__ blockoff) {
    int t = threadIdx.x, lane = t & 63, w = t >> 6;
    int v = (t < NBLK) ? blocksum[t] : 0;
    int incl = wave_incl_scan(v, lane);
    __shared__ int wsum[4];
    if (lane == 63) wsum[w] = incl;
    __syncthreads();
    int woff = 0;
    for (int j = 0; j < w; ++j) woff += wsum[j];
    incl += woff;
    if (t < NBLK) blockoff[t] = incl - v;
    if (t == NBLK - 1) blockoff[NBLK] = incl;
}

__global__ void k_scan_final(const int* __restrict__ deg, const int* __restrict__ blockoff,
                             int* __restrict__ rowptr, int* __restrict__ cursor) {
    int t = threadIdx.x, lane = t & 63, w = t >> 6;
    int i = blockIdx.x * 256 + t;
    int d = (i < N_NODES) ? deg[i] : 0;
    int incl = wave_incl_scan(d, lane);
    __shared__ int wsum[4];
    if (lane == 63) wsum[w] = incl;
    __syncthreads();
    int woff = 0;
    for (int j = 0; j < w; ++j) woff += wsum[j];
    int excl = incl - d + woff + blockoff[blockIdx.x];
    if (i < N_NODES) { rowptr[i] = excl; cursor[i] = excl; }
    if (i == 0) rowptr[N_NODES] = blockoff[NBLK];
}

__global__ void k_scatter(const int* __restrict__ row, const int* __restrict__ col,
                          const float* __restrict__ dinv, int* __restrict__ cursor,
                          int* __restrict__ csr_col, float* __restrict__ csr_nrm) {
    int e = blockIdx.x * 256 + threadIdx.x;
    if (e >= N_EDGES) return;
    int r = row[e], c = col[e];
    int pos = atomicAdd(&cursor[r], 1);
    csr_col[pos] = c;
    csr_nrm[pos] = dinv[r] * dinv[c];
}

// ---------------- weight transpose + bf16 hi/lo split ----------------

__global__ void k_wsplit(const float* __restrict__ W, u16* __restrict__ Whi,
                         u16* __restrict__ Wlo, int Kdim) {
    int idx = blockIdx.x * 256 + threadIdx.x;
    if (idx >= Kdim * 128) return;
    int k = idx >> 7, n = idx & 127;
    float f = W[idx];
    u16 hb = f2bf(f);
    u16 lb = f2bf(f - bf2f(hb));
    int p = ((k >> 3) & 3) ^ (n & 3);
    int kp = (k & ~31) | (p << 3) | (k & 7);
    Whi[(size_t)n * Kdim + kp] = hb;
    Wlo[(size_t)n * Kdim + kp] = lb;
}

// ---------------- MFMA GEMM: [M x K] f32 @ [K x 128] -> [M x 128] bf16 ----

template<int K, bool RELU>
__global__ void k_gemm_mfma(const float* __restrict__ A, const u16* __restrict__ Whi,
                            const u16* __restrict__ Wlo, u16* __restrict__ C, int M) {
    __shared__ u16 sAhi[64 * 32];
    __shared__ u16 sAlo[64 * 32];
    __shared__ u16 sBhi[128 * 32];
    __shared__ u16 sBlo[128 * 32];

    const int t = threadIdx.x;
    const int w = t >> 6;
    const int l = t & 63;
    const int ln = l & 15;
    const int h = l >> 4;
    const int row0 = blockIdx.x * 64;

    const int ar = t >> 2;
    const int aslot = t & 3;
    const int arow = row0 + ar;
    const bool aval = arow < M;
    const int aswz = (aslot ^ (ar & 3));
    const int bn = t >> 2;
    const int bs = t & 3;

    f32x4 acc[4][2];
    #pragma unroll
    for (int i = 0; i < 4; ++i)
        #pragma unroll
        for (int j = 0; j < 2; ++j)
            acc[i][j] = (f32x4){0.f, 0.f, 0.f, 0.f};

    for (int k0 = 0; k0 < K; k0 += 32) {
        float va[8];
        if (aval) {
            float4 v0 = *reinterpret_cast<const float4*>(A + (size_t)arow * K + k0 + aslot * 8);
            float4 v1 = *reinterpret_cast<const float4*>(A + (size_t)arow * K + k0 + aslot * 8 + 4);
            va[0] = v0.x; va[1] = v0.y; va[2] = v0.z; va[3] = v0.w;
            va[4] = v1.x; va[5] = v1.y; va[6] = v1.z; va[7] = v1.w;
        } else {
            #pragma unroll
            for (int q = 0; q < 8; ++q) va[q] = 0.f;
        }
        u16x8 hv, lv;
        #pragma unroll
        for (int q = 0; q < 8; ++q) {
            float f = va[q];
            if (RELU) f = fmaxf(f, 0.f);
            u16 hb = f2bf(f);
            hv[q] = hb;
            lv[q] = f2bf(f - bf2f(hb));
        }
        *reinterpret_cast<u16x8*>(sAhi + ar * 32 + aswz * 8) = hv;
        *reinterpret_cast<u16x8*>(sAlo + ar * 32 + aswz * 8) = lv;

        {
            const u16* gh0 = Whi + (size_t)bn * K + k0 + bs * 8;
            const u16* gh1 = Whi + (size_t)(bn + 64) * K + k0 + bs * 8;
            const u16* gl0 = Wlo + (size_t)bn * K + k0 + bs * 8;
            const u16* gl1 = Wlo + (size_t)(bn + 64) * K + k0 + bs * 8;
            *reinterpret_cast<uint4*>(sBhi + bn * 32 + bs * 8)        = *reinterpret_cast<const uint4*>(gh0);
            *reinterpret_cast<uint4*>(sBhi + (bn + 64) * 32 + bs * 8) = *reinterpret_cast<const uint4*>(gh1);
            *reinterpret_cast<uint4*>(sBlo + bn * 32 + bs * 8)        = *reinterpret_cast<const uint4*>(gl0);
            *reinterpret_cast<uint4*>(sBlo + (bn + 64) * 32 + bs * 8) = *reinterpret_cast<const uint4*>(gl1);
        }
        __syncthreads();

        short8 ah[4], al[4], bh[2], bl[2];
        #pragma unroll
        for (int i = 0; i < 4; ++i) {
            int r = i * 16 + ln;
            int idx = r * 32 + ((h ^ (r & 3)) << 3);
            ah[i] = *reinterpret_cast<const short8*>(sAhi + idx);
            al[i] = *reinterpret_cast<const short8*>(sAlo + idx);
        }
        #pragma unroll
        for (int j = 0; j < 2; ++j) {
            int n = w * 32 + j * 16 + ln;
            int idx = n * 32 + ((h ^ (n & 3)) << 3);
            bh[j] = *reinterpret_cast<const short8*>(sBhi + idx);
            bl[j] = *reinterpret_cast<const short8*>(sBlo + idx);
        }

        #pragma unroll
        for (int i = 0; i < 4; ++i)
            #pragma unroll
            for (int j = 0; j < 2; ++j) {
                acc[i][j] = __builtin_amdgcn_mfma_f32_16x16x32_bf16(ah[i], bh[j], acc[i][j], 0, 0, 0);
                acc[i][j] = __builtin_amdgcn_mfma_f32_16x16x32_bf16(ah[i], bl[j], acc[i][j], 0, 0, 0);
                acc[i][j] = __builtin_amdgcn_mfma_f32_16x16x32_bf16(al[i], bh[j], acc[i][j], 0, 0, 0);
            }
        __syncthreads();
    }

    #pragma unroll
    for (int i = 0; i < 4; ++i) {
        #pragma unroll
        for (int v = 0; v < 4; ++v) {
            int gr = row0 + i * 16 + h * 4 + v;
            if (gr < M) {
                #pragma unroll
                for (int j = 0; j < 2; ++j) {
                    int col = w * 32 + j * 16 + ln;
                    C[(size_t)gr * 128 + col] = f2bf(acc[i][j][v]);
                }
            }
        }
    }
}

// ---------------- GEMM: [M x 128] @ [128 x 40] -> [M x 40] ----------------

template<bool RELU>
__global__ void k_gemm40(const float* __restrict__ A, const float* __restrict__ W,
                         float* __restrict__ C, int M) {
    __shared__ float As[64][132];
    __shared__ float Ws[128][40];
    int t = threadIdx.x;
    int row0 = blockIdx.x * 64;
    #pragma unroll
    for (int i = 0; i < 8; ++i) {
        int fidx = t + i * 256;
        int r = fidx >> 5, c = (fidx & 31) << 2;
        int gr = row0 + r;
        float4 v = make_float4(0.f, 0.f, 0.f, 0.f);
        if (gr < M) v = *reinterpret_cast<const float4*>(A + (size_t)gr * 128 + c);
        if (RELU) {
            v.x = fmaxf(v.x, 0.f); v.y = fmaxf(v.y, 0.f);
            v.z = fmaxf(v.z, 0.f); v.w = fmaxf(v.w, 0.f);
        }
        *reinterpret_cast<float4*>(&As[r][c]) = v;
    }
    #pragma unroll
    for (int i = 0; i < 5; ++i) {
        int fidx = t + i * 256;
        int r = fidx / 10, c = (fidx % 10) << 2;
        float4 v = *reinterpret_cast<const float4*>(W + r * 40 + c);
        *reinterpret_cast<float4*>(&Ws[r][c]) = v;
    }
    __syncthreads();
    int r = t >> 2;
    int cg = t & 3;
    float acc[10];
    #pragma unroll
    for (int j = 0; j < 10; ++j) acc[j] = 0.0f;
    for (int k = 0; k < 128; ++k) {
        float a = As[r][k];
        #pragma unroll
        for (int j = 0; j < 10; ++j)
            acc[j] = fmaf(a, Ws[k][cg * 10 + j], acc[j]);
    }
    int gr = row0 + r;
    if (gr < M) {
        #pragma unroll
        for (int j = 0; j < 10; ++j)
            C[(size_t)gr * 40 + cg * 10 + j] = acc[j];
    }
}

// ---------------- CSR aggregation, bf16 h (NF=128) ----------------

__global__ void k_agg_csr_bf(const u16* __restrict__ h, const float* __restrict__ dinv,
                             const float* __restrict__ bias,
                             const int* __restrict__ rowptr, const int* __restrict__ csr_col,
                             const float* __restrict__ csr_nrm, float* __restrict__ out) {
    int gid = blockIdx.x * 256 + threadIdx.x;
    if (gid >= N_NODES * 32) return;
    int i = gid >> 5;
    int q = (gid & 31) * 4;
    float di = dinv[i];
    float s = di * di;
    ushort4 hv = *reinterpret_cast<const ushort4*>(h + (size_t)i * 128 + q);
    float4 bv = *reinterpret_cast<const float4*>(bias + q);
    float4 acc;
    acc.x = fmaf(bf2f(hv.x), s, bv.x);
    acc.y = fmaf(bf2f(hv.y), s, bv.y);
    acc.z = fmaf(bf2f(hv.z), s, bv.z);
    acc.w = fmaf(bf2f(hv.w), s, bv.w);
    int e = rowptr[i], e1 = rowptr[i + 1];
    for (; e + 1 < e1; e += 2) {
        int c0 = csr_col[e], c1 = csr_col[e + 1];
        float n0 = csr_nrm[e], n1 = csr_nrm[e + 1];
        ushort4 v0 = *reinterpret_cast<const ushort4*>(h + (size_t)c0 * 128 + q);
        ushort4 v1 = *reinterpret_cast<const ushort4*>(h + (size_t)c1 * 128 + q);
        acc.x = fmaf(bf2f(v0.x), n0, acc.x);
        acc.y = fmaf(bf2f(v0.y), n0, acc.y);
        acc.z = fmaf(bf2f(v0.z), n0, acc.z);
        acc.w = fmaf(bf2f(v0.w), n0, acc.w);
        acc.x = fmaf(bf2f(v1.x), n1, acc.x);
        acc.y = fmaf(bf2f(v1.y), n1, acc.y);
        acc.z = fmaf(bf2f(v1.z), n1, acc.z);
        acc.w = fmaf(bf2f(v1.w), n1, acc.w);
    }
    if (e < e1) {
        int c0 = csr_col[e];
        float n0 = csr_nrm[e];
        ushort4 v0 = *reinterpret_cast<const ushort4*>(h + (size_t)c0 * 128 + q);
        acc.x = fmaf(bf2f(v0.x), n0, acc.x);
        acc.y = fmaf(bf2f(v0.y), n0, acc.y);
        acc.z = fmaf(bf2f(v0.z), n0, acc.z);
        acc.w = fmaf(bf2f(v0.w), n0, acc.w);
    }
    *reinterpret_cast<float4*>(out + (size_t)i * 128 + q) = acc;
}

// ---------------- CSR aggregation, f32 h (NF=40, layer 3) ----------------

__global__ void k_agg_csr40(const float* __restrict__ h, const float* __restrict__ dinv,
                            const float* __restrict__ bias,
                            const int* __restrict__ rowptr, const int* __restrict__ csr_col,
                            const float* __restrict__ csr_nrm, float* __restrict__ out) {
    const int TPN = 10;
    int gid = blockIdx.x * 256 + threadIdx.x;
    if (gid >= N_NODES * TPN) return;
    int i = gid / TPN;
    int q = (gid % TPN) * 4;
    float di = dinv[i];
    float s = di * di;
    float4 hv = *reinterpret_cast<const float4*>(h + (size_t)i * 40 + q);
    float4 bv = *reinterpret_cast<const float4*>(bias + q);
    float4 acc;
    acc.x = fmaf(hv.x, s, bv.x);
    acc.y = fmaf(hv.y, s, bv.y);
    acc.z = fmaf(hv.z, s, bv.z);
    acc.w = fmaf(hv.w, s, bv.w);
    int e1 = rowptr[i + 1];
    for (int e = rowptr[i]; e < e1; ++e) {
        int c = csr_col[e];
        float nv = csr_nrm[e];
        float4 v = *reinterpret_cast<const float4*>(h + (size_t)c * 40 + q);
        acc.x = fmaf(v.x, nv, acc.x);
        acc.y = fmaf(v.y, nv, acc.y);
        acc.z = fmaf(v.z, nv, acc.z);
        acc.w = fmaf(v.w, nv, acc.w);
    }
    *reinterpret_cast<float4*>(out + (size_t)i * 40 + q) = acc;
}

// ---------------- log_softmax (in-place, one wave per row) ----------------

__global__ void k_logsoftmax(float* __restrict__ out) {
    int wave = threadIdx.x >> 6, lane = threadIdx.x & 63;
    int rowi = blockIdx.x * 4 + wave;
    if (rowi >= N_NODES) return;
    float v = (lane < NCLS) ? out[(size_t)rowi * NCLS + lane] : -INFINITY;
    float m = v;
    #pragma unroll
    for (int off = 32; off; off >>= 1) m = fmaxf(m, __shfl_xor(m, off));
    float ex = (lane < NCLS) ? expf(v - m) : 0.0f;
    float s = ex;
    #pragma unroll
    for (int off = 32; off; off >>= 1) s += __shfl_xor(s, off);
    float ls = logf(s);
    if (lane < NCLS) out[(size_t)rowi * NCLS + lane] = v - m - ls;
}

// ---------------- launch ----------------

extern "C" void kernel_launch(void* const* d_in, const int* in_sizes, int n_in,
                              void* d_out, int out_size, void* d_ws, size_t ws_size,
                              hipStream_t stream) {
    const float* x  = (const float*)d_in[0];
    const int* ei   = (const int*)d_in[1];
    const float* W1 = (const float*)d_in[2];
    const float* b1 = (const float*)d_in[3];
    const float* W2 = (const float*)d_in[4];
    const float* b2 = (const float*)d_in[5];
    const float* W3 = (const float*)d_in[6];
    const float* b3 = (const float*)d_in[7];
    float* out = (float*)d_out;

    const int* row = ei;             // targets
    const int* col = ei + N_EDGES;   // sources

    char* ws = (char*)d_ws;
    int*   deg      = (int*)ws;   ws += sizeof(int) * N_NODES;
    int*   rowptr   = (int*)ws;   ws += sizeof(int) * 50004;
    int*   cursor   = (int*)ws;   ws += sizeof(int) * N_NODES;
    int*   blocksum = (int*)ws;   ws += sizeof(int) * NBLK;
    int*   blockoff = (int*)ws;   ws += sizeof(int) * 204;
    int*   csr_col  = (int*)ws;   ws += sizeof(int) * N_EDGES;
    float* csr_nrm  = (float*)ws; ws += sizeof(float) * N_EDGES;
    float* dinv     = (float*)ws; ws += sizeof(float) * N_NODES;
    u16*   wt1hi    = (u16*)ws;   ws += sizeof(u16) * F_IN * 128;
    u16*   wt1lo    = (u16*)ws;   ws += sizeof(u16) * F_IN * 128;
    u16*   wt2hi    = (u16*)ws;   ws += sizeof(u16) * HID * 128;
    u16*   wt2lo    = (u16*)ws;   ws += sizeof(u16) * HID * 128;
    u16*   hbuf     = (u16*)ws;   ws += sizeof(u16) * (size_t)N_NODES * HID;
    float* abuf     = (float*)ws; ws += sizeof(float) * (size_t)N_NODES * HID;
    float* h3       = (float*)ws; ws += sizeof(float) * (size_t)N_NODES * NCLS;

    const int NB_N = (N_NODES + 255) / 256;
    const int NB_E = (N_EDGES + 255) / 256;
    const int NB_G = (N_NODES + 63) / 64;

    // weight split/transpose (once)
    k_wsplit<<<(F_IN * 128 + 255) / 256, 256, 0, stream>>>(W1, wt1hi, wt1lo, F_IN);
    k_wsplit<<<(HID * 128 + 255) / 256, 256, 0, stream>>>(W2, wt2hi, wt2lo, HID);

    // CSR build (once, shared by all 3 layers)
    k_zero_deg<<<NB_N, 256, 0, stream>>>(deg);
    k_count<<<NB_E, 256, 0, stream>>>(row, deg);
    k_dinv<<<NB_N, 256, 0, stream>>>(deg, dinv);
    k_scan_partial<<<NBLK, 256, 0, stream>>>(deg, blocksum);
    k_scan_block<<<1, 256, 0, stream>>>(blocksum, blockoff);
    k_scan_final<<<NBLK, 256, 0, stream>>>(deg, blockoff, rowptr, cursor);
    k_scatter<<<NB_E, 256, 0, stream>>>(row, col, dinv, cursor, csr_col, csr_nrm);

    // layer 1 (MFMA split-precision GEMM -> bf16 h)
    k_gemm_mfma<F_IN, false><<<NB_G, 256, 0, stream>>>(x, wt1hi, wt1lo, hbuf, N_NODES);
    k_agg_csr_bf<<<(N_NODES * 32 + 255) / 256, 256, 0, stream>>>(
        hbuf, dinv, b1, rowptr, csr_col, csr_nrm, abuf);

    // layer 2 (relu fused into GEMM A-staging)
    k_gemm_mfma<HID, true><<<NB_G, 256, 0, stream>>>(abuf, wt2hi, wt2lo, hbuf, N_NODES);
    k_agg_csr_bf<<<(N_NODES * 32 + 255) / 256, 256, 0, stream>>>(
        hbuf, dinv, b2, rowptr, csr_col, csr_nrm, abuf);

    // layer 3
    k_gemm40<true><<<NB_G, 256, 0, stream>>>(abuf, W3, h3, N_NODES);
    k_agg_csr40<<<(N_NODES * 10 + 255) / 256, 256, 0, stream>>>(
        h3, dinv, b3, rowptr, csr_col, csr_nrm, out);

    // log_softmax in-place
    k_logsoftmax<<<(N_NODES + 3) / 4, 256, 0, stream>>>(out);
}